// Round 5
// baseline (243.271 us; speedup 1.0000x reference)
//
#include <hip/hip_runtime.h>
#include <stdint.h>

#define B_ROWS 8192
#define INP    1024
#define HID    1024
#define MEMD   256
#define KIN    2304   // INP+HID+MEMD
#define KHM    1280   // HID+MEMD
#define NCAT   144    // 136 outputs padded to 144

typedef unsigned short u16;
typedef unsigned int   u32;
typedef __attribute__((ext_vector_type(8))) short bf16x8;
typedef __attribute__((ext_vector_type(4))) float f32x4;

__device__ __forceinline__ u32 f2bf_u32(float f) {
  u32 b = __builtin_bit_cast(u32, f);
  u32 r = b + 0x7FFF + ((b >> 16) & 1);   // RNE
  return r >> 16;
}
// pack 2 f32 -> u32 of 2 bf16 (lo in low half)
__device__ __forceinline__ u32 pk2(float lo, float hi) {
  return f2bf_u32(lo) | (f2bf_u32(hi) << 16);
}

__device__ __forceinline__ void gload16(const void* g, void* l) {
  __builtin_amdgcn_global_load_lds(
      (const __attribute__((address_space(1))) u32*)g,
      (__attribute__((address_space(3))) u32*)l, 16, 0, 0);
}

// ---- fused weight converter (the only pre-pass) ------------------------
// blocks 0..1151: Wh -> WhB (bf16). blocks 1152..1295: Wa/Wb/Wva/Wvb -> Wcat (+bcat).
__global__ void k_cvt_w(const float* __restrict__ Wh,
                        const float* __restrict__ Wa, const float* __restrict__ ba,
                        const float* __restrict__ Wb, const float* __restrict__ bb,
                        const float* __restrict__ Wva, const float* __restrict__ bva,
                        const float* __restrict__ Wvb, const float* __restrict__ bvb,
                        u16* __restrict__ WhB, u16* __restrict__ Wcat,
                        float* __restrict__ bcat) {
  const int blk = blockIdx.x;
  if (blk < 1152) {
    const int i = blk * 256 + threadIdx.x;          // 294,912 groups of 8
    const float* src = Wh + (size_t)i * 8;
    float4 v0 = ((const float4*)src)[0];
    float4 v1 = ((const float4*)src)[1];
    uint4 q = make_uint4(pk2(v0.x, v0.y), pk2(v0.z, v0.w),
                         pk2(v1.x, v1.y), pk2(v1.z, v1.w));
    *((uint4*)(WhB + (size_t)i * 8)) = q;
  } else {
    const int r = blk - 1152;   // 0..143
    const int t = threadIdx.x;
    const float* src = nullptr; float bias = 0.f;
    if      (r < 4)   { src = Wa  + (size_t)r        * KHM; bias = ba[r];      }
    else if (r < 8)   { src = Wb  + (size_t)(r - 4)  * KHM; bias = bb[r - 4];  }
    else if (r < 72)  { src = Wva + (size_t)(r - 8)  * KHM; bias = bva[r - 8]; }
    else if (r < 136) { src = Wvb + (size_t)(r - 72) * KHM; bias = bvb[r - 72];}
    if (t == 0) bcat[r] = bias;
    if (t < 160) {
      const int col = t * 8;
      uint4 q;
      if (src) {
        float4 v0 = ((const float4*)(src + col))[0];
        float4 v1 = ((const float4*)(src + col))[1];
        q = make_uint4(pk2(v0.x, v0.y), pk2(v0.z, v0.w),
                       pk2(v1.x, v1.y), pk2(v1.z, v1.w));
      } else {
        q = make_uint4(0, 0, 0, 0);
      }
      *((uint4*)(Wcat + (size_t)r * KHM + col)) = q;
    }
  }
}

// ---- GEMM1: h = relu([x|h0|mem] @ WhB^T + bh) --------------------------
// 128x128 tile, BK=64, 4 waves. A is staged from f32 sources with in-reg
// bf16 conversion + swizzled ds_write (T14 reg-staging); B via global_load_lds
// (inverse-swizzled source). Double-buffered, two barriers, counted vmcnt.
__global__ void __launch_bounds__(256, 2)
k_gemm1(const float* __restrict__ x, const float* __restrict__ h0,
        const float* __restrict__ mem, const u16* __restrict__ WhB,
        const float* __restrict__ bh, float* __restrict__ outH) {
  __shared__ u16 As[2][128 * 64];
  __shared__ u16 Bs[2][128 * 64];
  const int tid = threadIdx.x;
  const int bid = blockIdx.x;
  // XCD-aware swizzle: 512 blocks, 8 XCDs, 64 blocks/XCD (8 br x 8 bc each)
  const int swz = (bid & 7) * 64 + (bid >> 3);
  const int br = swz >> 3;   // 0..63 row tile
  const int bc = swz & 7;    // 0..7  col tile
  const int wid = tid >> 6, lane = tid & 63;
  const int wr = wid >> 1, wc = wid & 1;
  const int lr = lane & 15, lko = lane >> 4;

  const f32x4 vz = {0.f, 0.f, 0.f, 0.f};
  f32x4 acc[4][4];
#pragma unroll
  for (int m = 0; m < 4; ++m)
#pragma unroll
    for (int n = 0; n < 4; ++n) acc[m][n] = vz;

  const int sRow   = tid >> 3;                 // 0..31 (LDS row base; + q*32)
  const int sCol8  = tid & 7;                  // linear k-chunk for A source
  const int dSlot  = sCol8 ^ (sRow & 7);       // swizzled LDS slot (A write)
  const int sSlotG = sCol8 ^ (sRow & 7);       // swizzled source slot (B gload)
  const u16* gB = WhB + (size_t)(bc * 128 + sRow) * KIN + sSlotG * 8;

  // fragment read bases (swizzled slots)
  const int sx  = lr & 7;
  const int s0  = ((0 + lko) ^ sx) * 8;   // kk=0  slot
  const int s1  = ((4 + lko) ^ sx) * 8;   // kk=32 slot
  const int axr = (wr * 64 + lr) * 64;    // + m*1024
  const int bxr = (wc * 64 + lr) * 64;    // + n*1024

  // A-source pointer for K-window kt: cols [kt*64, kt*64+64)
  auto srcBase = [&](int kt) -> const float* {
    if (kt < 16) return x   + (size_t)(br * 128 + sRow) * 1024 + kt * 64 + sCol8 * 8;
    if (kt < 32) return h0  + (size_t)(br * 128 + sRow) * 1024 + (kt - 16) * 64 + sCol8 * 8;
    return            mem + (size_t)(br * 128 + sRow) * 256  + (kt - 32) * 64 + sCol8 * 8;
  };
  auto srcStride = [&](int kt) -> int { return (kt < 32) ? 1024 : 256; };

  float4 pre[4][2];

  // prologue: stage tile 0 (A via regs+cvt, B via gload_lds)
  {
    const float* p = srcBase(0);
    const int st = srcStride(0);
#pragma unroll
    for (int q = 0; q < 4; ++q) {
      pre[q][0] = ((const float4*)(p + (size_t)(q * 32) * st))[0];
      pre[q][1] = ((const float4*)(p + (size_t)(q * 32) * st))[1];
    }
#pragma unroll
    for (int q = 0; q < 4; ++q)
      gload16(gB + (size_t)(q * 32) * KIN, &Bs[0][q * 2048 + tid * 8]);
#pragma unroll
    for (int q = 0; q < 4; ++q) {
      uint4 pk = make_uint4(pk2(pre[q][0].x, pre[q][0].y), pk2(pre[q][0].z, pre[q][0].w),
                            pk2(pre[q][1].x, pre[q][1].y), pk2(pre[q][1].z, pre[q][1].w));
      *((uint4*)&As[0][(q * 32 + sRow) * 64 + dSlot * 8]) = pk;
    }
  }

  const int NKT = KIN / 64;   // 36
  for (int kt = 0; kt < NKT; ++kt) {
    const int cur = kt & 1, nxt = 1 - cur;
    if (kt < NKT - 1) {
      const float* p = srcBase(kt + 1);
      const int st = srcStride(kt + 1);
#pragma unroll
      for (int q = 0; q < 4; ++q) {
        pre[q][0] = ((const float4*)(p + (size_t)(q * 32) * st))[0];
        pre[q][1] = ((const float4*)(p + (size_t)(q * 32) * st))[1];
      }
      const int kofs = (kt + 1) * 64;
#pragma unroll
      for (int q = 0; q < 4; ++q)
        gload16(gB + (size_t)(q * 32) * KIN + kofs, &Bs[nxt][q * 2048 + tid * 8]);
      // retire tile-kt B gloads (kt+1's 8 A-loads + 4 B-gloads stay in flight);
      // lgkmcnt(0) drains prologue/step-e ds_writes before the barrier
      asm volatile("s_waitcnt vmcnt(12) lgkmcnt(0)" ::: "memory");
    } else {
      asm volatile("s_waitcnt vmcnt(0) lgkmcnt(0)" ::: "memory");
    }
    __builtin_amdgcn_s_barrier();           // #1: buf[cur] ready for all waves
    __builtin_amdgcn_sched_barrier(0);

    const u16* Ac = &As[cur][0];
    const u16* Bc = &Bs[cur][0];
    {
      bf16x8 a[4], b[4];
#pragma unroll
      for (int m = 0; m < 4; ++m) a[m] = *(const bf16x8*)&Ac[axr + m * 1024 + s0];
#pragma unroll
      for (int n = 0; n < 4; ++n) b[n] = *(const bf16x8*)&Bc[bxr + n * 1024 + s0];
      __builtin_amdgcn_s_setprio(1);
#pragma unroll
      for (int m = 0; m < 4; ++m)
#pragma unroll
        for (int n = 0; n < 4; ++n)
          acc[m][n] = __builtin_amdgcn_mfma_f32_16x16x32_bf16(a[m], b[n], acc[m][n], 0, 0, 0);
      __builtin_amdgcn_s_setprio(0);
    }
    {
      bf16x8 a[4], b[4];
#pragma unroll
      for (int m = 0; m < 4; ++m) a[m] = *(const bf16x8*)&Ac[axr + m * 1024 + s1];
#pragma unroll
      for (int n = 0; n < 4; ++n) b[n] = *(const bf16x8*)&Bc[bxr + n * 1024 + s1];
      __builtin_amdgcn_s_setprio(1);
#pragma unroll
      for (int m = 0; m < 4; ++m)
#pragma unroll
        for (int n = 0; n < 4; ++n)
          acc[m][n] = __builtin_amdgcn_mfma_f32_16x16x32_bf16(a[m], b[n], acc[m][n], 0, 0, 0);
      __builtin_amdgcn_s_setprio(0);
    }
    __builtin_amdgcn_sched_barrier(0);

    if (kt < NKT - 1) {
      // A(kt+1) regs have arrived by now (compiler also guards its own uses)
      asm volatile("s_waitcnt vmcnt(4)" ::: "memory");
#pragma unroll
      for (int q = 0; q < 4; ++q) {
        uint4 pk = make_uint4(pk2(pre[q][0].x, pre[q][0].y), pk2(pre[q][0].z, pre[q][0].w),
                              pk2(pre[q][1].x, pre[q][1].y), pk2(pre[q][1].z, pre[q][1].w));
        *((uint4*)&As[nxt][(q * 32 + sRow) * 64 + dSlot * 8]) = pk;
      }
      asm volatile("s_waitcnt lgkmcnt(0)" ::: "memory");
    }
    __builtin_amdgcn_s_barrier();           // #2: protect As[nxt]/Bs reuse
  }

  const int rowBase = br * 128 + wr * 64;
  const int colBase = bc * 128 + wc * 64;
#pragma unroll
  for (int n = 0; n < 4; ++n) {
    const int col = colBase + n * 16 + lr;
    const float bias = bh[col];
#pragma unroll
    for (int m = 0; m < 4; ++m) {
#pragma unroll
      for (int r = 0; r < 4; ++r) {
        const int row = rowBase + m * 16 + lko * 4 + r;
        float v = fmaxf(acc[m][n][r] + bias, 0.0f);
        outH[(size_t)row * HID + col] = v;
      }
    }
  }
}

// ---- GEMM2 + tail: u = [h|mem] @ Wcat^T + bcat ; memory update ---------
// Split-K across 4 waves, 16 rows/block, 512 blocks. A-fragments converted
// in-reg from outH/mem f32; B from bf16 Wcat (L2-resident). No LDS staging.
__device__ __forceinline__ float p5(float x) {
  float a = fabsf(x);
  float a2 = a * a;
  return a2 * a2 * a;
}

__global__ void __launch_bounds__(256, 2)
k_gemm2(const float* __restrict__ hfull, const float* __restrict__ memf,
        const u16* __restrict__ Wcat, const float* __restrict__ bcat,
        float* __restrict__ outM) {
  __shared__ float pS[4][16][148];
  const int tid = threadIdx.x;
  const int bid = blockIdx.x;           // 512 blocks of 16 rows
  const int wid = tid >> 6, lane = tid & 63;
  const int lr = lane & 15, lko = lane >> 4;
  const int rowBase = bid * 16;

  const f32x4 vz = {0.f, 0.f, 0.f, 0.f};
  f32x4 acc[9];
#pragma unroll
  for (int n = 0; n < 9; ++n) acc[n] = vz;

  const u16* gB = Wcat + (size_t)lr * KHM + lko * 8;

  // wave w handles k64-chunks {c*4 + w : c=0..4}
#pragma unroll
  for (int c = 0; c < 5; ++c) {
    const int ck = c * 4 + wid;
    const float* gAf = (ck < 16)
        ? hfull + (size_t)(rowBase + lr) * 1024 + ck * 64 + lko * 8
        : memf  + (size_t)(rowBase + lr) * 256  + (ck - 16) * 64 + lko * 8;
#pragma unroll
    for (int h = 0; h < 2; ++h) {
      float4 a0 = ((const float4*)(gAf + h * 32))[0];
      float4 a1 = ((const float4*)(gAf + h * 32))[1];
      union { u32 w[4]; bf16x8 v; } ap;
      ap.w[0] = pk2(a0.x, a0.y); ap.w[1] = pk2(a0.z, a0.w);
      ap.w[2] = pk2(a1.x, a1.y); ap.w[3] = pk2(a1.z, a1.w);
      const int ko = ck * 64 + h * 32;
      bf16x8 b[9];
#pragma unroll
      for (int n = 0; n < 9; ++n)
        b[n] = *(const bf16x8*)(gB + (size_t)(n * 16) * KHM + ko);
#pragma unroll
      for (int n = 0; n < 9; ++n)
        acc[n] = __builtin_amdgcn_mfma_f32_16x16x32_bf16(ap.v, b[n], acc[n], 0, 0, 0);
    }
  }

  // write per-wave partials (row = lko*4+r, col = n*16+lr)
#pragma unroll
  for (int n = 0; n < 9; ++n)
#pragma unroll
    for (int r = 0; r < 4; ++r)
      pS[wid][lko * 4 + r][n * 16 + lr] = acc[n][r];
  __syncthreads();

  // reduce 4 partials + bias -> pS[0]
  {
    const int rr = tid >> 4;            // 0..15
    const int cb = (tid & 15) * 9;      // 0..135
#pragma unroll
    for (int i = 0; i < 9; ++i) {
      const int col = cb + i;
      float s = pS[0][rr][col] + pS[1][rr][col] + pS[2][rr][col] + pS[3][rr][col]
              + bcat[col];
      pS[0][rr][col] = s;
    }
  }
  __syncthreads();

  // tail: 16 threads per row
  const int r = tid >> 4;
  const int t = tid & 15;
  const float* U = &pS[0][r][0];

  float S1a = 0.f, S1b = 0.f;
  {
    const float4* Ua = (const float4*)(U + 40);
    const float4* Ub = (const float4*)(U + 104);
#pragma unroll
    for (int i = 0; i < 8; ++i) {
      float4 va = Ua[i], vb = Ub[i];
      S1a += p5(va.x) + p5(va.y) + p5(va.z) + p5(va.w);
      S1b += p5(vb.x) + p5(vb.y) + p5(vb.z) + p5(vb.w);
    }
  }

  float sa[4], sb[4];
#pragma unroll
  for (int k = 0; k < 4; ++k) {
    const float4* Pa = (const float4*)(U + 8 + 8 * k);
    const float4* Pb = (const float4*)(U + 72 + 8 * k);
    float4 a0v = Pa[0], a1v = Pa[1], b0v = Pb[0], b1v = Pb[1];
    float S0a = p5(a0v.x) + p5(a0v.y) + p5(a0v.z) + p5(a0v.w)
              + p5(a1v.x) + p5(a1v.y) + p5(a1v.z) + p5(a1v.w);
    float S0b = p5(b0v.x) + p5(b0v.y) + p5(b0v.z) + p5(b0v.w)
              + p5(b1v.x) + p5(b1v.y) + p5(b1v.z) + p5(b1v.w);
    float na = exp2f(0.2f * log2f(S0a * S1a));   // (S0*S1)^(1/5)
    float nb = exp2f(0.2f * log2f(S0b * S1b));
    sa[k] = 0.25f * U[k]     / fmaxf(na, 1e-12f);
    sb[k] = 0.25f * U[4 + k] / fmaxf(nb, 1e-12f);
  }

  // this thread covers memory cols [t*16, t*16+16) -> j0 = t>>1 fixed
  const int j0 = t >> 1;
  float A0 = 0.f, B0 = 0.f;
#pragma unroll
  for (int k = 0; k < 4; ++k) {
    A0 += sa[k] * U[8  + 8 * k + j0];
    B0 += sb[k] * U[72 + 8 * k + j0];
  }

  const int i1b = (t & 1) * 16;
  const size_t rowg = (size_t)(rowBase + r);
  const float4* memR = (const float4*)(memf + rowg * MEMD + t * 16);
  float4*       outR = (float4*)      (outM + rowg * MEMD + t * 16);
#pragma unroll
  for (int j = 0; j < 4; ++j) {
    float4 mv = memR[j];
    float4 ua = *(const float4*)(U + 40  + i1b + j * 4);
    float4 ub = *(const float4*)(U + 104 + i1b + j * 4);
    float4 o;
    o.x = mv.x + A0 * ua.x - B0 * ub.x;
    o.y = mv.y + A0 * ua.y - B0 * ub.y;
    o.z = mv.z + A0 * ua.z - B0 * ub.z;
    o.w = mv.w + A0 * ua.w - B0 * ub.w;
    outR[j] = o;
  }
}

// ---- launch ------------------------------------------------------------
extern "C" void kernel_launch(void* const* d_in, const int* in_sizes, int n_in,
                              void* d_out, int out_size, void* d_ws, size_t ws_size,
                              hipStream_t stream) {
  const float* x   = (const float*)d_in[0];
  const float* h0  = (const float*)d_in[1];
  const float* mem = (const float*)d_in[2];
  const float* Wh  = (const float*)d_in[3];
  const float* bh  = (const float*)d_in[4];
  const float* Wa  = (const float*)d_in[5];
  const float* ba  = (const float*)d_in[6];
  const float* Wb  = (const float*)d_in[7];
  const float* bb  = (const float*)d_in[8];
  const float* Wva = (const float*)d_in[9];
  const float* bva = (const float*)d_in[10];
  const float* Wvb = (const float*)d_in[11];
  const float* bvb = (const float*)d_in[12];

  float* outM = (float*)d_out;                          // 8192*256
  float* outH = (float*)d_out + (size_t)B_ROWS * MEMD;  // 8192*1024

  char* ws = (char*)d_ws;
  u16*   WhB  = (u16*)(ws);                  // 1024*2304*2 = 4,718,592
  u16*   Wcat = (u16*)(ws + 4718592);        // 144*1280*2  =   368,640
  float* bcat = (float*)(ws + 5087232);      // 144*4

  k_cvt_w <<<dim3(1296), dim3(256), 0, stream>>>(Wh, Wa, ba, Wb, bb,
                                                 Wva, bva, Wvb, bvb,
                                                 WhB, Wcat, bcat);
  k_gemm1 <<<dim3(512),  dim3(256), 0, stream>>>(x, h0, mem, WhB, bh, outH);
  k_gemm2 <<<dim3(512),  dim3(256), 0, stream>>>(outH, mem, Wcat, bcat, outM);
}